// Round 4
// baseline (413.263 us; speedup 1.0000x reference)
//
#include <hip/hip_runtime.h>
#include <hip/hip_bf16.h>
#include <stdint.h>

// Problem constants (B, N, E, D) = (32, 4096, 8192, 128); all float io fp32.
// R3 post-mortem: gemm 116us latency-bound (occ 22%, LDS 52KB -> 3 blk/CU,
// MfmaUtil 8.8%); gather ~100us with 64MB agg HBM round-trip. R4: gather
// fused into gemm (A-fragments built in-register from bucket lists), single
// LDS buffer + launch_bounds(256,4) -> 4 blk/CU, 3 dispatches total.
#define BB 32
#define NN 4096
#define EE 8192
#define DD 128
#define MM (BB * NN)        // 131072 rows
#define THREE_D (3 * DD)    // 384
#define CAP 32              // bucket capacity; deg~Poisson(2), P(deg>31)~1e-25

typedef __bf16 bf16x8 __attribute__((ext_vector_type(8)));
typedef float  f32x4  __attribute__((ext_vector_type(4)));

// ws layout
#define WT_BYTES  ((size_t)2 * THREE_D * DD * 2)  // 192 KiB bf16 [mat][col][k]
#define CNT_OFF   WT_BYTES
#define CNT_BYTES ((size_t)MM * 4)                // 512 KiB
#define BKT_OFF   (CNT_OFF + CNT_BYTES)           // 16 MiB edge-id buckets

// ---------------------------------------------------------------------------
// Kernel 1 (prep): blocks [0,384) transpose+cvt weights (D,3D)->bf16 (3D,D);
// blocks [384,1408) build CSR buckets (atomicAdd on counters, store edge id).
// ---------------------------------------------------------------------------
__global__ void prep(const float* __restrict__ w0, const float* __restrict__ w1,
                     __bf16* __restrict__ wt, const int* __restrict__ conn,
                     int* __restrict__ counts, int* __restrict__ bucket) {
    int bid = blockIdx.x;
    if (bid < 384) {
        int tid = bid * 256 + threadIdx.x;             // 0 .. 98303
        int mat = tid / (THREE_D * DD);
        int rem = tid % (THREE_D * DD);
        int col = rem / DD;
        int k   = rem % DD;
        const float* src = mat ? w1 : w0;
        wt[tid] = (__bf16)src[k * THREE_D + col];
    } else {
        int e = (bid - 384) * 256 + threadIdx.x;       // 0 .. B*E-1
        int b = e >> 13;                               // e / EE
        int tgt = conn[e * 2 + 1];
        int node = b * NN + tgt;
        int pos = atomicAdd(&counts[node], 1);
        if (pos < CAP) bucket[node * CAP + pos] = e;
    }
}

// ---------------------------------------------------------------------------
// Kernel 2: fused gather + dual-GEMM + GRU gates.
// Block: 256 thr = 4 waves, 128 rows (= 128 nodes); wave owns 2 M-tiles of
// 16 rows. Prologue: per lane, gather its 128-B k-slice of each incident
// message row (avg deg 2), fp32-sum, cvt bf16 -> A-fragment mat0; h rows
// cvt -> mat1. Then 8 gate-col groups of 16: block stages 24 KB of weights
// into one LDS buffer (COLP=136 pad -> 2-way-free banks), 24 ds_read_b128 +
// 48 MFMA per g, fused gate epilogue.
// MFMA layouts (gfx950, verified): A[m=lane&15][k=quad*8+j],
// B[k=quad*8+j][n=lane&15], C/D: col=lane&15, row=quad*4+reg.
// ---------------------------------------------------------------------------
#define COLP 136   // padded col stride in elements (272 B)
__launch_bounds__(256, 4)
__global__ void gru_gemm(const float* __restrict__ messages,
                         const int* __restrict__ counts,
                         const int* __restrict__ bucket,
                         const float* __restrict__ h_in,
                         const __bf16* __restrict__ wt,
                         const float* __restrict__ bias,
                         float* __restrict__ out) {
    const int wave = threadIdx.x >> 6;
    const int lane = threadIdx.x & 63;
    const int quad = lane >> 4;
    const int l16  = lane & 15;
    const int row0 = blockIdx.x * 128 + wave * 32;

    __shared__ __align__(16) __bf16 lb[6 * 16 * COLP];  // 25.5 KiB

    // A fragments: [mat][mt][ko]; mat 0 = gathered messages, 1 = h
    bf16x8 afrag[2][2][4];
    for (int mt = 0; mt < 2; ++mt) {
        int node = row0 + mt * 16 + l16;
        const float* hrow = h_in + (size_t)node * DD;
        for (int ko = 0; ko < 4; ++ko) {
            int k = ko * 32 + quad * 8;
            f32x4 h0 = *(const f32x4*)(hrow + k);
            f32x4 h1 = *(const f32x4*)(hrow + k + 4);
            bf16x8 hg;
            for (int i = 0; i < 4; ++i) {
                hg[i]     = (__bf16)h0[i];
                hg[i + 4] = (__bf16)h1[i];
            }
            afrag[1][mt][ko] = hg;
        }
        // gather this node's incident message rows (lane's k-slice)
        int cnt = counts[node];
        if (cnt > CAP) cnt = CAP;
        f32x4 s[8];
        #pragma unroll
        for (int i = 0; i < 8; ++i) s[i] = (f32x4){0.f, 0.f, 0.f, 0.f};
        for (int i = 0; i < cnt; ++i) {
            int e = bucket[node * CAP + i];
            const float* mrow = messages + (size_t)e * DD + quad * 8;
            #pragma unroll
            for (int ko = 0; ko < 4; ++ko) {
                s[2 * ko]     += *(const f32x4*)(mrow + ko * 32);
                s[2 * ko + 1] += *(const f32x4*)(mrow + ko * 32 + 4);
            }
        }
        #pragma unroll
        for (int ko = 0; ko < 4; ++ko) {
            bf16x8 ag;
            for (int i = 0; i < 4; ++i) {
                ag[i]     = (__bf16)s[2 * ko][i];
                ag[i + 4] = (__bf16)s[2 * ko + 1][i];
            }
            afrag[0][mt][ko] = ag;
        }
    }

    for (int g = 0; g < 8; ++g) {
        __syncthreads();                               // lb reads of g-1 done
        for (int c = threadIdx.x; c < 1536; c += 256) {
            int slice = c >> 8;                        // m*3+p, 0..5
            int rem   = c & 255;
            int col   = rem >> 4;                      // 0..15
            int ch    = rem & 15;                      // 16-B chunk, 0..15
            int m = slice / 3, p = slice % 3;
            bf16x8 v = *(const bf16x8*)(wt
                + ((size_t)(m * THREE_D + p * 128 + g * 16 + col)) * DD + ch * 8);
            *(bf16x8*)&lb[(slice * 16 + col) * COLP + ch * 8] = v;
        }
        __syncthreads();                               // lb staged

        f32x4 acc[2][3][2];                            // [mt][part z/r/h][mat]
        for (int mt = 0; mt < 2; ++mt)
            for (int p = 0; p < 3; ++p)
                for (int m = 0; m < 2; ++m)
                    acc[mt][p][m] = (f32x4){0.f, 0.f, 0.f, 0.f};

        for (int ko = 0; ko < 4; ++ko) {
            for (int p = 0; p < 3; ++p) {
                for (int m = 0; m < 2; ++m) {
                    bf16x8 bfrag = *(const bf16x8*)&lb
                        [((m * 3 + p) * 16 + l16) * COLP + ko * 32 + quad * 8];
                    for (int mt = 0; mt < 2; ++mt)
                        acc[mt][p][m] = __builtin_amdgcn_mfma_f32_16x16x32_bf16(
                            afrag[m][mt][ko], bfrag, acc[mt][p][m], 0, 0, 0);
                }
            }
        }

        int j = g * 16 + l16;                          // gate index 0..127
        float b0z = bias[j];
        float b0r = bias[DD + j];
        float b0h = bias[2 * DD + j];
        float b1z = bias[THREE_D + j];
        float b1r = bias[THREE_D + DD + j];
        float b1h = bias[THREE_D + 2 * DD + j];

        for (int mt = 0; mt < 2; ++mt) {
            for (int rr = 0; rr < 4; ++rr) {
                int row = row0 + mt * 16 + quad * 4 + rr;
                float xz = acc[mt][0][0][rr] + b0z;
                float rz = acc[mt][0][1][rr] + b1z;
                float xr = acc[mt][1][0][rr] + b0r;
                float rrg = acc[mt][1][1][rr] + b1r;
                float xh = acc[mt][2][0][rr] + b0h;
                float rh = acc[mt][2][1][rr] + b1h;
                float z  = 1.f / (1.f + __expf(-(xz + rz)));
                float rg = 1.f / (1.f + __expf(-(xr + rrg)));
                float pre = xh + rg * rh;
                float hh = 2.f / (1.f + __expf(-2.f * pre)) - 1.f;   // tanh
                float hold = h_in[(size_t)row * DD + j];
                float o = z * hold + (1.f - z) * hh;
                out[(size_t)row * DD + j] = o;
            }
        }
    }
}

// ---------------------------------------------------------------------------
extern "C" void kernel_launch(void* const* d_in, const int* in_sizes, int n_in,
                              void* d_out, int out_size, void* d_ws, size_t ws_size,
                              hipStream_t stream) {
    const float* atom_state = (const float*)d_in[0];
    const float* messages   = (const float*)d_in[1];
    const int*   conn       = (const int*)d_in[2];
    const float* w0         = (const float*)d_in[3];
    const float* w1         = (const float*)d_in[4];
    const float* bias       = (const float*)d_in[5];
    float* out = (float*)d_out;

    __bf16* wt     = (__bf16*)d_ws;
    int*    counts = (int*)((char*)d_ws + CNT_OFF);
    int*    bucket = (int*)((char*)d_ws + BKT_OFF);

    hipMemsetAsync(counts, 0, CNT_BYTES, stream);
    prep<<<384 + (BB * EE) / 256, 256, 0, stream>>>(w0, w1, wt, conn, counts, bucket);
    gru_gemm<<<MM / 128, 256, 0, stream>>>(messages, counts, bucket,
                                           atom_state, wt, bias, out);
}